// Round 7
// baseline (212.866 us; speedup 1.0000x reference)
//
#include <hip/hip_runtime.h>
#include <math.h>

#define TOPK 4
#define TILE_LOG 11
#define TILE (1 << TILE_LOG)      // 2048 edges per tile (= mean edges of 64 nodes)
#define PAD 256                   // staged overhang: covers segments crossing tile end
#define STAGE (TILE + PAD)        // 2304 floats = 9216 B LDS
#define BLOCK_A 256
#define BLOCK_B 128               // node span per tile ~ 64 +- 8 (Poisson); 128 = +8 sigma

// ---- Kernel A: invert row_ptr -> first node starting in each edge-tile ----
__global__ __launch_bounds__(BLOCK_A) void tile_first_kernel(
    const int* __restrict__ row_ptr, unsigned* __restrict__ first_node, int n_nodes)
{
    int n = blockIdx.x * BLOCK_A + threadIdx.x;
    if (n >= n_nodes) return;
    int t = row_ptr[n] >> TILE_LOG;
    atomicMin(&first_node[t], (unsigned)n);
}

// ---- Kernel B: edge-tiled top-4. Bulk DMA address is STATIC (blockIdx only):
// issues at wave start with zero dependency, fully coalesced. ----
__global__ __launch_bounds__(BLOCK_B) void segment_top4_kernel(
    const int* __restrict__ row_ptr,
    const float* __restrict__ scores,
    const unsigned* __restrict__ first_node,
    float* __restrict__ vals_out,   // [N,4] float32
    float* __restrict__ idx_out,    // [N,4] indices as float32
    int n_nodes, int n_edges)
{
    __shared__ float lds_buf[STAGE + 4];   // +4: masked unroll overread pad

    int t     = blockIdx.x;
    int cbase = t << TILE_LOG;                       // static!
    int stage_n = min(STAGE, n_edges - cbase);       // multiple of 4 for this E
    int n4      = stage_n >> 2;

    // Fire-and-forget global->LDS DMA, all rounds back-to-back, no waits.
    // LDS dest must be wave-uniform base + lane*16: (q & ~63) is wave-uniform.
    for (int k = 0; k * BLOCK_B < n4; ++k) {
        int q = k * BLOCK_B + (int)threadIdx.x;
        if (q < n4) {
            __builtin_amdgcn_global_load_lds(
                (const __attribute__((address_space(1))) void*)(scores + cbase + 4 * q),
                (__attribute__((address_space(3))) void*)(lds_buf + 4 * (q & ~63)),
                16, 0, 0);
        }
    }

    // Overlap with DMA: fetch tile's node range + speculative row_ptr pair.
    unsigned first = first_node[t];
    int tile_end_edge = min(cbase + TILE, n_edges);
    int n0 = (first != 0xFFFFFFFFu) ? (int)first + (int)threadIdx.x : n_nodes;
    int sb0 = 0, se0 = 0;
    if (n0 < n_nodes) { sb0 = row_ptr[n0]; se0 = row_ptr[n0 + 1]; }

    __syncthreads();   // vmcnt(0)+barrier: DMA complete, LDS visible

    // Branchless insertion, strict '>' keeps smaller edge index on ties
    // (matches reference). sc = -inf never inserts.
    int staged_end = cbase + stage_n;
    for (int n = n0; n < n_nodes; n += BLOCK_B) {
        int sb = (n == n0) ? sb0 : row_ptr[n];
        if (sb >= tile_end_edge) break;              // node starts in a later tile
        int se = (n == n0) ? se0 : row_ptr[n + 1];

        float v0 = -INFINITY, v1 = -INFINITY, v2 = -INFINITY, v3 = -INFINITY;
        int   i0 = -1, i1 = -1, i2 = -1, i3 = -1;
        auto ins = [&](float sc, int id) {
            bool g0 = sc > v0, g1 = sc > v1, g2 = sc > v2, g3 = sc > v3;
            v3 = g3 ? (g2 ? v2 : sc) : v3;  i3 = g3 ? (g2 ? i2 : id) : i3;
            v2 = g2 ? (g1 ? v1 : sc) : v2;  i2 = g2 ? (g1 ? i1 : id) : i2;
            v1 = g1 ? (g0 ? v0 : sc) : v1;  i1 = g1 ? (g0 ? i0 : id) : i1;
            v0 = g0 ? sc : v0;              i0 = g0 ? id : i0;
        };

        // LDS part (sb >= cbase guaranteed: row_ptr[first] >= cbase, monotone).
        int lds_hi = min(se, staged_end);
        for (int e = sb; e < lds_hi; e += 4) {
            int l = e - cbase;
            float s0 = lds_buf[l];
            float s1 = lds_buf[l + 1];
            float s2 = lds_buf[l + 2];
            float s3 = lds_buf[l + 3];
            int rem = lds_hi - e;
            ins(s0, e);
            ins(rem > 1 ? s1 : -INFINITY, e + 1);
            ins(rem > 2 ? s2 : -INFINITY, e + 2);
            ins(rem > 3 ? s3 : -INFINITY, e + 3);
        }
        // Global fallback for segments overrunning the staged pad (~never).
        for (int e = (sb > staged_end ? sb : staged_end); e < se; ++e)
            ins(scores[e], e);

        float4 vout = make_float4(v0, v1, v2, v3);
        *(float4*)(vals_out + (size_t)n * 4) = vout;
        float4 iout = make_float4((float)i0, (float)i1, (float)i2, (float)i3);
        *(float4*)(idx_out + (size_t)n * 4) = iout;
    }
}

extern "C" void kernel_launch(void* const* d_in, const int* in_sizes, int n_in,
                              void* d_out, int out_size, void* d_ws, size_t ws_size,
                              hipStream_t stream)
{
    const int*   row_ptr = (const int*)d_in[0];
    const float* scores  = (const float*)d_in[1];
    int n_nodes = in_sizes[0] - 1;
    int n_edges = in_sizes[1];
    int n_tiles = (n_edges + TILE - 1) / TILE;

    unsigned* first_node = (unsigned*)d_ws;

    float* out      = (float*)d_out;
    float* vals_out = out;                           // first N*4 floats
    float* idx_out  = out + (size_t)n_nodes * TOPK;  // next N*4 floats (idx as f32)

    // ws is re-poisoned to 0xAA before every timed launch: re-init every call.
    hipMemsetAsync(first_node, 0xFF, (size_t)n_tiles * sizeof(unsigned), stream);

    tile_first_kernel<<<(n_nodes + BLOCK_A - 1) / BLOCK_A, BLOCK_A, 0, stream>>>(
        row_ptr, first_node, n_nodes);

    segment_top4_kernel<<<n_tiles, BLOCK_B, 0, stream>>>(
        row_ptr, scores, first_node, vals_out, idx_out, n_nodes, n_edges);
}

// Round 8
// 116.462 us; speedup vs baseline: 1.8278x; 1.8278x over previous
//
#include <hip/hip_runtime.h>
#include <math.h>

#define TOPK 4
#define WAVE 64
#define ROUNDS 9                 // 9 DMA rounds x 64 lanes x 16 B = 9216 B / tile
#define STAGE (ROUNDS * 256)     // 2304 floats staged per tile (mean 2048 + 5.6 sigma)
#define GRID 2048                // 8 single-wave blocks per CU (LDS 2x9.2KB -> 8/CU)

// Fire-and-forget global->LDS DMA for one tile. LDS dest is wave-uniform
// (hardware places lane i at dst + 16*i). Source clamped in-array; clamped
// lanes write garbage that the scan bounds never read.
__device__ __forceinline__ void dma_tile(const float* __restrict__ scores,
                                         int base, int clamp_hi, float* dst, int lane)
{
#pragma unroll
    for (int r = 0; r < ROUNDS; ++r) {
        int src = base + (r << 8) + (lane << 2);
        src = src < clamp_hi ? src : clamp_hi;
        __builtin_amdgcn_global_load_lds(
            (const __attribute__((address_space(1))) void*)(scores + src),
            (__attribute__((address_space(3))) void*)(dst + (r << 8)),
            16, 0, 0);
    }
}

__global__ __launch_bounds__(WAVE) void segment_top4_kernel(
    const int* __restrict__ row_ptr,
    const float* __restrict__ scores,
    float* __restrict__ vals_out,   // [N,4] float32
    float* __restrict__ idx_out,    // [N,4] indices as float32
    int n_nodes, int n_edges, int n_tiles)
{
    __shared__ float lds[2][STAGE + 4];   // +4: unroll-by-4 overread pad

    int t = blockIdx.x;
    if (t >= n_tiles) return;
    int lane = threadIdx.x;
    int G = gridDim.x;
    int clamp_hi = n_edges - 4;

    // Prologue: tile t's DMA + per-lane segment bounds.
    int base = row_ptr[t << 6] & ~15;                 // uniform -> s_load
    dma_tile(scores, base, clamp_hi, lds[0], lane);
    int node = (t << 6) + lane;
    int sb = 0, se = 0;
    if (node < n_nodes) { sb = row_ptr[node]; se = row_ptr[node + 1]; }

    int cur = 0;
    while (true) {
        int tn = t + G;
        bool has_next = (tn < n_tiles);               // block-uniform branch
        int nbase = 0, nsb = 0, nse = 0;
        if (has_next) {
            // Prefetch next tile's bounds BEFORE its DMA (fence pins order),
            // so at the wait below the 9 newest vmem ops are exactly the DMA.
            int nnode = (tn << 6) + lane;
            if (nnode < n_nodes) { nsb = row_ptr[nnode]; nse = row_ptr[nnode + 1]; }
            nbase = row_ptr[tn << 6] & ~15;           // uniform -> s_load (lgkm)
            asm volatile("" ::: "memory");            // compile-time order fence
            dma_tile(scores, nbase, clamp_hi, lds[cur ^ 1], lane);
            // AITER-style partial drain: wait for everything EXCEPT the 9
            // just-issued next-tile DMAs -> tile t's data is in LDS while
            // 9.2 KB stays in flight through the entire scan. Never vmcnt(0).
            asm volatile("s_waitcnt vmcnt(9)" ::: "memory");
        } else {
            asm volatile("s_waitcnt vmcnt(0)" ::: "memory");
        }

        // ---- scan tile t from lds[cur] ----
        // key = mono(score)<<32 | ~edge_idx : u64 compare gives (score desc,
        // index asc) exactly; keys unique so strict '>' matches the reference
        // tie-break. key 0 (masked) never inserts.
        unsigned long long k0 = 0, k1 = 0, k2 = 0, k3 = 0;
        auto ins = [&](unsigned long long k) {
            bool g0 = k > k0, g1 = k > k1, g2 = k > k2, g3 = k > k3;
            k3 = g3 ? (g2 ? k2 : k) : k3;
            k2 = g2 ? (g1 ? k1 : k) : k2;
            k1 = g1 ? (g0 ? k0 : k) : k1;
            k0 = g0 ? k : k0;
        };
        auto mkkey = [](float s, int e) -> unsigned long long {
            unsigned u = __float_as_uint(s);
            u ^= 0x80000000u | (unsigned)((int)u >> 31);   // order-preserving map
            return ((unsigned long long)u << 32) | (unsigned)(~e);
        };

        const float* buf = lds[cur];
        int lim = min(se, base + STAGE);
        for (int e = sb; e < lim; e += 4) {
            int l = e - base;
            float s0 = buf[l];
            float s1 = buf[l + 1];
            float s2 = buf[l + 2];
            float s3 = buf[l + 3];
            int rem = lim - e;
            ins(mkkey(s0, e));
            ins(rem > 1 ? mkkey(s1, e + 1) : 0ULL);
            ins(rem > 2 ? mkkey(s2, e + 2) : 0ULL);
            ins(rem > 3 ? mkkey(s3, e + 3) : 0ULL);
        }
        // Overflow fallback: segment runs past the staged window (~never).
        for (int e = max(sb, base + STAGE); e < se; ++e)
            ins(mkkey(scores[e], e));

        // ---- decode + store ----
        if (node < n_nodes) {
            auto dec = [](unsigned long long k, float& v, float& fi) {
                if (k == 0) { v = -INFINITY; fi = -1.0f; return; }
                unsigned hi = (unsigned)(k >> 32);
                unsigned lo = (unsigned)k;
                unsigned su = (hi & 0x80000000u) ? (hi ^ 0x80000000u) : ~hi;
                v = __uint_as_float(su);
                fi = (float)(int)(~lo);
            };
            float4 vo, io;
            dec(k0, vo.x, io.x); dec(k1, vo.y, io.y);
            dec(k2, vo.z, io.z); dec(k3, vo.w, io.w);
            *(float4*)(vals_out + (size_t)node * 4) = vo;
            *(float4*)(idx_out + (size_t)node * 4) = io;
        }

        if (!has_next) break;
        t = tn; node = (tn << 6) + lane;
        sb = nsb; se = nse; base = nbase; cur ^= 1;
    }
}

extern "C" void kernel_launch(void* const* d_in, const int* in_sizes, int n_in,
                              void* d_out, int out_size, void* d_ws, size_t ws_size,
                              hipStream_t stream)
{
    const int*   row_ptr = (const int*)d_in[0];
    const float* scores  = (const float*)d_in[1];
    int n_nodes = in_sizes[0] - 1;
    int n_edges = in_sizes[1];
    int n_tiles = (n_nodes + 63) >> 6;

    float* out      = (float*)d_out;
    float* vals_out = out;                           // first N*4 floats
    float* idx_out  = out + (size_t)n_nodes * TOPK;  // next N*4 floats (idx as f32)

    int grid = n_tiles < GRID ? n_tiles : GRID;
    segment_top4_kernel<<<grid, WAVE, 0, stream>>>(
        row_ptr, scores, vals_out, idx_out, n_nodes, n_edges, n_tiles);
}